// Round 14
// baseline (246.283 us; speedup 1.0000x reference)
//
#include <hip/hip_runtime.h>
#include <math.h>

typedef unsigned short u16;
typedef unsigned int u32;
typedef __bf16 bf16x8 __attribute__((ext_vector_type(8)));
typedef float f32x4 __attribute__((ext_vector_type(4)));
typedef float f32x16 __attribute__((ext_vector_type(16)));

__device__ __forceinline__ u16 f2bf(float f) {
  unsigned u = __float_as_uint(f);
  u += 0x7fff + ((u >> 16) & 1);   // RNE
  return (u16)(u >> 16);
}

__device__ __forceinline__ float b2f(u16 x) {
  return __uint_as_float((u32)x << 16);
}

__device__ __forceinline__ u32 cvtpk(float lo, float hi) {
  u32 r;
  asm("v_cvt_pk_bf16_f32 %0, %1, %2" : "=v"(r) : "v"(lo), "v"(hi));
  return r;
}

// v_permlane32_swap_b32 x, y:  x' = [x.lo32lanes, y.lo32lanes],
//                              y' = [x.hi32lanes, y.hi32lanes]
__device__ __forceinline__ void pswap(u32& x, u32& y) {
  asm volatile("v_permlane32_swap_b32 %0, %1" : "+v"(x), "+v"(y));
}

__device__ __forceinline__ void gload_lds16(const void* g, void* l) {
  __builtin_amdgcn_global_load_lds(
      (const __attribute__((address_space(1))) unsigned int*)g,
      (__attribute__((address_space(3))) unsigned int*)l, 16, 0, 0);
}

// ---------------- fp32 -> bf16 convert, 5 x 4M-element tensors in one launch --
__global__ __launch_bounds__(256) void k_cvt5(const float* __restrict__ s0,
                                              const float* __restrict__ s1,
                                              const float* __restrict__ s2,
                                              const float* __restrict__ s3,
                                              const float* __restrict__ s4,
                                              u16* __restrict__ dx,
                                              u16* __restrict__ dqkv,
                                              u16* __restrict__ dwo) {
  const int y = blockIdx.y;
  const float* s = (y == 0) ? s0 : (y == 1) ? s1 : (y == 2) ? s2
                   : (y == 3) ? s3 : s4;
  u16* d = (y == 0) ? dx : (y == 4) ? dwo : dqkv + (size_t)(y - 1) * 4194304;
  int i = (blockIdx.x * 256 + threadIdx.x) * 4;
  float4 v = *(const float4*)(s + i);
  ushort4 o;
  o.x = f2bf(v.x); o.y = f2bf(v.y); o.z = f2bf(v.z); o.w = f2bf(v.w);
  *(ushort4*)(d + i) = o;
}

// ---------------- zero the 256 pair-counters (graph-replay safe) --------------
__global__ __launch_bounds__(256) void k_zero(int* __restrict__ cnt) {
  cnt[threadIdx.x] = 0;
}

// ---------------- big GEMM: C[M,N] = A[M,K] * B[N,K]^T, bf16 out ---------------
// 128x192 tile, BK=64, 512 thr (8 waves 2Mx4N, 64x48/wave). Counted-vmcnt
// double-buffered pipeline, raw s_barrier, XOR-swizzled LDS, kk-split MFMA
// (12 MFMA before the barrier under lgkmcnt(7)). 80K LDS -> 2 blocks/CU.
__global__ __launch_bounds__(512, 4) void k_gemm_big(const u16* __restrict__ A,
                                                     const u16* __restrict__ B,
                                                     u16* __restrict__ C,
                                                     int M, int N, int K) {
  __shared__ __align__(16) char lds[2][40960];   // per buf: A 16K | B 24K
  const int tid = threadIdx.x;
  const int wid = tid >> 6, lane = tid & 63;
  const int lr = lane & 15, lg = lane >> 4;
  const int wm = (wid >> 2) * 64, wn = (wid & 3) * 48;
  const int nbx = N / 192, nby = M >> 7;
  const int colsPerXcd = nbx >> 3;
  const int xcd = blockIdx.x & 7, idx = blockIdx.x >> 3;
  const int bx = xcd * colsPerXcd + idx / nby;
  const int by = idx % nby;
  const int bm = by * 128, bn = bx * 192;
  const int srow = tid >> 3;                     // 64 rows per issue
  const int schunk = (tid & 7) ^ (srow & 7);     // pre-swizzled 16B chunk
  const size_t rsK = (size_t)K * 2;              // row stride, bytes
  const char* gA = (const char*)A + (size_t)(bm + srow) * rsK + schunk * 16;
  const char* gB = (const char*)B + (size_t)(bn + srow) * rsK + schunk * 16;
  char* dA = (char*)lds + wid * 1024;            // wave-uniform dest bases
  char* dB = (char*)lds + 16384 + wid * 1024;

#define STAGE(cur, k0)                                                         \
  {                                                                            \
    _Pragma("unroll") for (int i = 0; i < 2; ++i)                              \
        gload_lds16(gA + (size_t)(i * 64) * rsK + (size_t)(k0) * 2,            \
                    dA + (cur) * 40960 + i * 8192);                            \
    _Pragma("unroll") for (int i = 0; i < 3; ++i)                              \
        gload_lds16(gB + (size_t)(i * 64) * rsK + (size_t)(k0) * 2,            \
                    dB + (cur) * 40960 + i * 8192);                            \
  }

  f32x4 acc[4][3] = {};
  STAGE(0, 0);
  STAGE(1, 64);
  asm volatile("s_waitcnt vmcnt(5)" ::: "memory");   // tile0 landed
  __builtin_amdgcn_s_barrier();
  const int NT = K >> 6;
  int cur = 0;
  const int rsw = (lr & 7);
  for (int t = 0; t < NT; ++t) {
    const char* La = (const char*)lds + cur * 40960;
    const char* Lb = La + 16384;
    bf16x8 af0[4], bf0[3], af1[4], bf1[3];
#pragma unroll
    for (int mi = 0; mi < 4; ++mi)
      af0[mi] = *(const bf16x8*)(La + (wm + mi * 16 + lr) * 128 +
                                 ((lg ^ rsw) * 16));
#pragma unroll
    for (int ni = 0; ni < 3; ++ni)
      bf0[ni] = *(const bf16x8*)(Lb + (wn + ni * 16 + lr) * 128 +
                                 ((lg ^ rsw) * 16));
    __builtin_amdgcn_sched_barrier(0);           // pin kk0-burst before kk1
#pragma unroll
    for (int mi = 0; mi < 4; ++mi)
      af1[mi] = *(const bf16x8*)(La + (wm + mi * 16 + lr) * 128 +
                                 (((4 + lg) ^ rsw) * 16));
#pragma unroll
    for (int ni = 0; ni < 3; ++ni)
      bf1[ni] = *(const bf16x8*)(Lb + (wn + ni * 16 + lr) * 128 +
                                 (((4 + lg) ^ rsw) * 16));
    asm volatile("s_waitcnt lgkmcnt(7)" ::: "memory");  // kk0 frags ready
    __builtin_amdgcn_sched_barrier(0);
    __builtin_amdgcn_s_setprio(1);
#pragma unroll
    for (int mi = 0; mi < 4; ++mi)
#pragma unroll
      for (int ni = 0; ni < 3; ++ni)
        acc[mi][ni] = __builtin_amdgcn_mfma_f32_16x16x32_bf16(
            af0[mi], bf0[ni], acc[mi][ni], 0, 0, 0);
    __builtin_amdgcn_s_setprio(0);
    asm volatile("s_waitcnt lgkmcnt(0)" ::: "memory");
    __builtin_amdgcn_sched_barrier(0);
    __builtin_amdgcn_s_barrier();                       // all waves done w/ cur
    if (t + 2 < NT) STAGE(cur, (t + 2) << 6);           // overwrite cur (safe)
    __builtin_amdgcn_s_setprio(1);
#pragma unroll
    for (int mi = 0; mi < 4; ++mi)
#pragma unroll
      for (int ni = 0; ni < 3; ++ni)
        acc[mi][ni] = __builtin_amdgcn_mfma_f32_16x16x32_bf16(
            af1[mi], bf1[ni], acc[mi][ni], 0, 0, 0);
    __builtin_amdgcn_s_setprio(0);
    if (t + 2 < NT)
      asm volatile("s_waitcnt vmcnt(5)" ::: "memory");  // t+1 landed, t+2 flying
    else
      asm volatile("s_waitcnt vmcnt(0)" ::: "memory");  // tail: drain
    __builtin_amdgcn_s_barrier();
    cur ^= 1;
  }
#undef STAGE
#pragma unroll
  for (int mi = 0; mi < 4; ++mi)
#pragma unroll
    for (int ni = 0; ni < 3; ++ni)
#pragma unroll
      for (int j = 0; j < 4; ++j)
        C[(size_t)(bm + wm + mi * 16 + lg * 4 + j) * N + bn + wn + ni * 16 + lr] =
            f2bf(acc[mi][ni][j]);
}

// ---------------- pipelined GEMM 128x64 (+bias): final projection -------------
__global__ __launch_bounds__(256, 2) void k_gemm_pipe(const u16* __restrict__ A,
                                                      const u16* __restrict__ B,
                                                      const float* __restrict__ bias,
                                                      float* __restrict__ C,
                                                      int M, int N, int K) {
  __shared__ __align__(16) char lds[2][24576];   // per buf: A 16K | B 8K
  const int tid = threadIdx.x;
  const int wid = tid >> 6, lane = tid & 63;
  const int lr = lane & 15, lg = lane >> 4;
  const int wm = (wid >> 1) * 64, wn = (wid & 1) * 32;
  const int nbx = N >> 6, nby = M >> 7;
  const int colsPerXcd = nbx >> 3;
  const int xcd = blockIdx.x & 7, idx = blockIdx.x >> 3;
  const int bx = xcd * colsPerXcd + idx / nby;
  const int by = idx % nby;
  const int bm = by * 128, bn = bx * 64;
  const int srow = tid >> 3;                     // 32 rows per issue
  const int schunk = (tid & 7) ^ (srow & 7);
  const size_t rsK = (size_t)K * 2;
  const char* gA = (const char*)A + (size_t)(bm + srow) * rsK + schunk * 16;
  const char* gB = (const char*)B + (size_t)(bn + srow) * rsK + schunk * 16;
  char* dA = (char*)lds + wid * 1024;
  char* dB = (char*)lds + 16384 + wid * 1024;

#define STAGE(cur, k0)                                                         \
  {                                                                            \
    _Pragma("unroll") for (int i = 0; i < 4; ++i)                              \
        gload_lds16(gA + (size_t)(i * 32) * rsK + (size_t)(k0) * 2,            \
                    dA + (cur) * 24576 + i * 4096);                            \
    _Pragma("unroll") for (int i = 0; i < 2; ++i)                              \
        gload_lds16(gB + (size_t)(i * 32) * rsK + (size_t)(k0) * 2,            \
                    dB + (cur) * 24576 + i * 4096);                            \
  }

  f32x4 acc[4][2] = {};
  STAGE(0, 0);
  STAGE(1, 64);
  asm volatile("s_waitcnt vmcnt(6)" ::: "memory");   // tile0 landed
  __builtin_amdgcn_s_barrier();
  const int NT = K >> 6;
  int cur = 0;
  const int rsw = (lr & 7);
  for (int t = 0; t < NT; ++t) {
    const char* La = (const char*)lds + cur * 24576;
    const char* Lb = La + 16384;
    bf16x8 af0[4], bf0[2], af1[4], bf1[2];
#pragma unroll
    for (int mi = 0; mi < 4; ++mi)
      af0[mi] = *(const bf16x8*)(La + (wm + mi * 16 + lr) * 128 +
                                 ((lg ^ rsw) * 16));
#pragma unroll
    for (int ni = 0; ni < 2; ++ni)
      bf0[ni] = *(const bf16x8*)(Lb + (wn + ni * 16 + lr) * 128 +
                                 ((lg ^ rsw) * 16));
    __builtin_amdgcn_sched_barrier(0);
#pragma unroll
    for (int mi = 0; mi < 4; ++mi)
      af1[mi] = *(const bf16x8*)(La + (wm + mi * 16 + lr) * 128 +
                                 (((4 + lg) ^ rsw) * 16));
#pragma unroll
    for (int ni = 0; ni < 2; ++ni)
      bf1[ni] = *(const bf16x8*)(Lb + (wn + ni * 16 + lr) * 128 +
                                 (((4 + lg) ^ rsw) * 16));
    asm volatile("s_waitcnt lgkmcnt(6)" ::: "memory");  // kk0 frags ready
    __builtin_amdgcn_sched_barrier(0);
    __builtin_amdgcn_s_setprio(1);
#pragma unroll
    for (int mi = 0; mi < 4; ++mi)
#pragma unroll
      for (int ni = 0; ni < 2; ++ni)
        acc[mi][ni] = __builtin_amdgcn_mfma_f32_16x16x32_bf16(
            af0[mi], bf0[ni], acc[mi][ni], 0, 0, 0);
    __builtin_amdgcn_s_setprio(0);
    asm volatile("s_waitcnt lgkmcnt(0)" ::: "memory");
    __builtin_amdgcn_sched_barrier(0);
    __builtin_amdgcn_s_barrier();
    if (t + 2 < NT) STAGE(cur, (t + 2) << 6);
    __builtin_amdgcn_s_setprio(1);
#pragma unroll
    for (int mi = 0; mi < 4; ++mi)
#pragma unroll
      for (int ni = 0; ni < 2; ++ni)
        acc[mi][ni] = __builtin_amdgcn_mfma_f32_16x16x32_bf16(
            af1[mi], bf1[ni], acc[mi][ni], 0, 0, 0);
    __builtin_amdgcn_s_setprio(0);
    if (t + 2 < NT)
      asm volatile("s_waitcnt vmcnt(6)" ::: "memory");
    else
      asm volatile("s_waitcnt vmcnt(0)" ::: "memory");
    __builtin_amdgcn_s_barrier();
    cur ^= 1;
  }
#undef STAGE
#pragma unroll
  for (int mi = 0; mi < 4; ++mi)
#pragma unroll
    for (int ni = 0; ni < 2; ++ni) {
      int col = bn + wn + ni * 16 + lr;
      float bb = bias[col];
#pragma unroll
      for (int j = 0; j < 4; ++j)
        C[(size_t)(bm + wm + mi * 16 + lg * 4 + j) * N + col] =
            acc[mi][ni][j] + bb;
    }
}

// ---------------- RMSNorm(+bias) + RoPE, bf16 in -> bf16 out -----------------
// q additionally pre-scaled by 1/sqrt(HD) * log2(e)  (attention uses exp2)
__global__ __launch_bounds__(256) void k_rmsnorm_rope(
    const u16* __restrict__ qkv, const float* __restrict__ bq,
    const float* __restrict__ bk, const float* __restrict__ gq,
    const float* __restrict__ gk, const float* __restrict__ fcos,
    const float* __restrict__ fsin, u16* __restrict__ qb, u16* __restrict__ kb) {
  const int s = blockIdx.x, which = blockIdx.y;
  const int t = threadIdx.x;
  const u16* src = qkv + (size_t)s * 6144 + which * 2048;
  const float* bias = which ? bk : bq;
  const float* g = which ? gk : gq;
  u16* dst = (which ? kb : qb) + (size_t)s * 2048;
  const int c0 = t * 8;
  uint4 raw = *(const uint4*)(src + c0);         // 8 bf16
  const u16* rp = (const u16*)&raw;
  float4 b0 = *(const float4*)(bias + c0);
  float4 b1 = *(const float4*)(bias + c0 + 4);
  float v[8];
  v[0] = b2f(rp[0]) + b0.x; v[1] = b2f(rp[1]) + b0.y;
  v[2] = b2f(rp[2]) + b0.z; v[3] = b2f(rp[3]) + b0.w;
  v[4] = b2f(rp[4]) + b1.x; v[5] = b2f(rp[5]) + b1.y;
  v[6] = b2f(rp[6]) + b1.z; v[7] = b2f(rp[7]) + b1.w;
  float ss = 0.f;
#pragma unroll
  for (int j = 0; j < 8; ++j) ss += v[j] * v[j];
#pragma unroll
  for (int m = 1; m < 64; m <<= 1) ss += __shfl_xor(ss, m);
  __shared__ float red[4];
  if ((t & 63) == 0) red[t >> 6] = ss;
  __syncthreads();
  float r = rsqrtf((red[0] + red[1] + red[2] + red[3]) * (1.0f / 2048.0f) + 1e-6f);
  if (!which) r *= 0.08838834764831843f * 1.4426950408889634f;
  float4 g0 = *(const float4*)(g + c0);
  float4 g1 = *(const float4*)(g + c0 + 4);
  float gg[8] = {g0.x, g0.y, g0.z, g0.w, g1.x, g1.y, g1.z, g1.w};
  const int p0 = (c0 & 127) >> 1;
  u16 o[8];
#pragma unroll
  for (int j = 0; j < 4; ++j) {
    float a = v[2 * j] * r * gg[2 * j];
    float b = v[2 * j + 1] * r * gg[2 * j + 1];
    float co = fcos[s * 64 + p0 + j], si = fsin[s * 64 + p0 + j];
    o[2 * j]     = f2bf(a * co - b * si);
    o[2 * j + 1] = f2bf(a * si + b * co);
  }
  ushort4 q0; q0.x = o[0]; q0.y = o[1]; q0.z = o[2]; q0.w = o[3];
  ushort4 q1; q1.x = o[4]; q1.y = o[5]; q1.z = o[6]; q1.w = o[7];
  *(ushort4*)(dst + c0) = q0;
  *(ushort4*)(dst + c0 + 4) = q1;
}

// ---------------- V: bias + transpose -> vT[h*128+d][s] bf16 -----------------
__global__ __launch_bounds__(256) void k_transpose_v(const u16* __restrict__ qkv,
                                                     const float* __restrict__ bv,
                                                     u16* __restrict__ vT) {
  __shared__ float tile[64][65];
  const int s0 = blockIdx.x * 64, d0 = blockIdx.y * 64;
  const int t = threadIdx.x;
  const int tc = (t & 15) * 4, tr = t >> 4;
  float4 bb = *(const float4*)(bv + d0 + tc);
#pragma unroll
  for (int i = 0; i < 4; ++i) {
    int sr = tr + i * 16;
    ushort4 x = *(const ushort4*)(qkv + (size_t)(s0 + sr) * 6144 + 4096 + d0 + tc);
    tile[sr][tc + 0] = b2f(x.x) + bb.x;
    tile[sr][tc + 1] = b2f(x.y) + bb.y;
    tile[sr][tc + 2] = b2f(x.z) + bb.z;
    tile[sr][tc + 3] = b2f(x.w) + bb.w;
  }
  __syncthreads();
#pragma unroll
  for (int i = 0; i < 4; ++i) {
    int dr = tr + i * 16;
    ushort4 o;
    o.x = f2bf(tile[tc + 0][dr]);
    o.y = f2bf(tile[tc + 1][dr]);
    o.z = f2bf(tile[tc + 2][dr]);
    o.w = f2bf(tile[tc + 3][dr]);
    *(ushort4*)(vT + (size_t)(d0 + dr) * 2048 + s0 + tc) = o;
  }
}

// ---------------- flash attention: swapped QK^T, in-register softmax ----------
// flat grid 512, decode: xcd (bid&7) owns heads {2x,2x+1}; ksplit=2 with
// LOSER-MERGE: each (h,qt) pair's two blocks store partials + (m,l), bump an
// atomic counter; the second-arriving block reads the other's partials
// (L2-hot), combines in-register, writes bf16 ao. No separate merge kernel.
// Core loop identical to r10/r13 (proven): K,V dbuf, tree softmax, T13,
// cvt_pk+permlane, o4 MFMA-lsum.
__global__ __launch_bounds__(256, 2) void k_attn(const u16* __restrict__ qb,
                                                 const u16* __restrict__ kb,
                                                 const u16* __restrict__ vT,
                                                 float* __restrict__ opart,
                                                 float2* __restrict__ ml,
                                                 int* __restrict__ cnt,
                                                 u16* __restrict__ ao) {
  __shared__ __align__(16) char Ks[2][16384];    // K tile [64 keys][128 d]
  __shared__ __align__(16) char Vs[2][16384];    // V tile [128 d][64 k]
  const int bid = blockIdx.x;
  const int xcd = bid & 7, j = bid >> 3;         // j in 0..63
  const int h = xcd * 2 + (j & 1);
  const int qt = (j >> 1) & 15;
  const int ks = j >> 5;
  const int pair = h * 16 + qt;
  const int tid = threadIdx.x;
  const int wid = tid >> 6, lane = tid & 63;
  const int l31 = lane & 31, hi = lane >> 5;
  const int q0w = qt * 128 + wid * 32;
  const char* kbB = (const char*)kb;
  const char* vTB = (const char*)vT;
  const int krow = tid >> 4;                     // K: 16 rows/issue, 256B rows
  const int kc = (tid & 15) ^ krow;              // 4-bit XOR (16 chunks/row)
  const int vrow = tid >> 3;                     // V: 32 rows/issue, 128B rows
  const int vc = (tid & 7) ^ (vrow & 7);         // 3-bit XOR (8 chunks/row)

#define STAGE(buf, k0)                                                         \
  {                                                                            \
    _Pragma("unroll") for (int i = 0; i < 4; ++i)                              \
        gload_lds16(kbB + (size_t)((k0) + i * 16 + krow) * 4096 + h * 256 +    \
                        kc * 16,                                               \
                    (char*)Ks + (buf) * 16384 + i * 4096 + wid * 1024);        \
    _Pragma("unroll") for (int i = 0; i < 4; ++i)                              \
        gload_lds16(vTB + (size_t)(h * 128 + i * 32 + vrow) * 4096 +           \
                        (size_t)(k0) * 2 + vc * 16,                            \
                    (char*)Vs + (buf) * 16384 + i * 4096 + wid * 1024);        \
  }

  // Q fragments: B-operand, col q = l31, d-elems = ds*16 + hi*8 .. +8
  bf16x8 qf[8];
#pragma unroll
  for (int ds = 0; ds < 8; ++ds)
    qf[ds] = *(const bf16x8*)(qb + (size_t)(q0w + l31) * 2048 + h * 128 +
                              ds * 16 + hi * 8);
  f32x16 o[4] = {};                              // O[q reg-mapped][dt*32+l31]
  f32x16 o4 = {};                                // row-sum accumulator (V==1)
  float mrun = -3.0e38f;
  const int kbeg = ks * 1024;
  const int ksw = l31 & 15, vsw = l31 & 7;       // read-side swizzle keys
  union { u32 w[4]; bf16x8 v; } onesu;
  onesu.w[0] = 0x3F803F80u; onesu.w[1] = 0x3F803F80u;
  onesu.w[2] = 0x3F803F80u; onesu.w[3] = 0x3F803F80u;
  const bf16x8 vones = onesu.v;
  STAGE(0, kbeg);
  __syncthreads();
  int cur = 0;
  for (int t = 0; t < 16; ++t) {
    if (t + 1 < 16) STAGE(cur ^ 1, kbeg + (t + 1) * 64);
    const char* Kc = Ks[cur];
    const char* Vc = Vs[cur];
    // QK^T swapped: p[h2] = K[h2*32..+32) x Q  -> D[k][q]
    f32x16 p0 = {}, p1 = {};
    __builtin_amdgcn_s_setprio(1);
#pragma unroll
    for (int ds = 0; ds < 8; ++ds) {
      bf16x8 kf0 = *(const bf16x8*)(Kc + l31 * 256 + (((ds * 2 + hi) ^ ksw) * 16));
      p0 = __builtin_amdgcn_mfma_f32_32x32x16_bf16(kf0, qf[ds], p0, 0, 0, 0);
      bf16x8 kf1 = *(const bf16x8*)(Kc + (32 + l31) * 256 +
                                    (((ds * 2 + hi) ^ ksw) * 16));
      p1 = __builtin_amdgcn_mfma_f32_32x32x16_bf16(kf1, qf[ds], p1, 0, 0, 0);
    }
    __builtin_amdgcn_s_setprio(0);
    // row max: pairwise tree, depth 5
    {
      float tm[8];
#pragma unroll
      for (int r = 0; r < 8; ++r)
        tm[r] = fmaxf(fmaxf(p0[2 * r], p0[2 * r + 1]),
                      fmaxf(p1[2 * r], p1[2 * r + 1]));
#pragma unroll
      for (int s = 4; s > 0; s >>= 1)
#pragma unroll
        for (int r = 0; r < s; ++r) tm[r] = fmaxf(tm[r], tm[r + s]);
      float pm = fmaxf(tm[0], __shfl_xor(tm[0], 32));
      // T13 defer-rescale (log2 domain, THR=8 -> P bounded by 2^8)
      if (!__all(pm <= mrun + 8.0f)) {
        float nm = fmaxf(mrun, pm);
        float fv = __builtin_amdgcn_exp2f(mrun - nm);
#pragma unroll
        for (int dt = 0; dt < 4; ++dt) o[dt] *= fv;
        o4 *= fv;
        mrun = nm;
      }
    }
#pragma unroll
    for (int r = 0; r < 16; ++r) p0[r] = __builtin_amdgcn_exp2f(p0[r] - mrun);
#pragma unroll
    for (int r = 0; r < 16; ++r) p1[r] = __builtin_amdgcn_exp2f(p1[r] - mrun);
    // P -> PA fragments via cvt_pk + permlane32_swap (no LDS roundtrip)
    bf16x8 pa[4];
#pragma unroll
    for (int sl = 0; sl < 2; ++sl) {
      u32 E0 = cvtpk(p0[8 * sl + 0], p0[8 * sl + 1]);
      u32 E1 = cvtpk(p0[8 * sl + 2], p0[8 * sl + 3]);
      u32 O0 = cvtpk(p0[8 * sl + 4], p0[8 * sl + 5]);
      u32 O1 = cvtpk(p0[8 * sl + 6], p0[8 * sl + 7]);
      pswap(E0, O0); pswap(E1, O1);
      union { u32 w[4]; bf16x8 v; } uu;
      uu.w[0] = E0; uu.w[1] = E1; uu.w[2] = O0; uu.w[3] = O1;
      pa[sl] = uu.v;
    }
#pragma unroll
    for (int sl = 0; sl < 2; ++sl) {
      u32 E0 = cvtpk(p1[8 * sl + 0], p1[8 * sl + 1]);
      u32 E1 = cvtpk(p1[8 * sl + 2], p1[8 * sl + 3]);
      u32 O0 = cvtpk(p1[8 * sl + 4], p1[8 * sl + 5]);
      u32 O1 = cvtpk(p1[8 * sl + 6], p1[8 * sl + 7]);
      pswap(E0, O0); pswap(E1, O1);
      union { u32 w[4]; bf16x8 v; } uu;
      uu.w[0] = E0; uu.w[1] = E1; uu.w[2] = O0; uu.w[3] = O1;
      pa[2 + sl] = uu.v;
    }
    // PV: O[q][d] += PA[q][16k] x V[16k][32d]; o4 += PA x ones (row-sum)
    __builtin_amdgcn_s_setprio(1);
#pragma unroll
    for (int s = 0; s < 4; ++s) {
#pragma unroll
      for (int dt = 0; dt < 4; ++dt) {
        bf16x8 vf = *(const bf16x8*)(Vc + (dt * 32 + l31) * 128 +
                                     (((s * 2 + hi) ^ vsw) * 16));
        o[dt] = __builtin_amdgcn_mfma_f32_32x32x16_bf16(pa[s], vf, o[dt], 0, 0, 0);
      }
      o4 = __builtin_amdgcn_mfma_f32_32x32x16_bf16(pa[s], vones, o4, 0, 0, 0);
    }
    __builtin_amdgcn_s_setprio(0);
    __syncthreads();                             // stage done + bufs consumed
    cur ^= 1;
  }
#undef STAGE
  // lsum for q = l31 from o4 (r13-verified extraction)
  float lsum_q;
  {
    const int rsel = (l31 & 3) | (((l31 >> 3) & 3) << 2);
    float cand = o4[0];
#pragma unroll
    for (int r = 1; r < 16; ++r) cand = (rsel == r) ? o4[r] : cand;
    float other = __shfl_xor(cand, 32);
    lsum_q = (hi == ((l31 >> 2) & 1)) ? cand : other;
  }
  // ---- store own partials (coalesced [chunk][lane] layout) ----
  float* op = opart + ((size_t)pair * 2 + ks) * 16384 + wid * 4096;
#pragma unroll
  for (int dt = 0; dt < 4; ++dt)
#pragma unroll
    for (int rr = 0; rr < 4; ++rr) {
      f32x4 sl;
      sl[0] = o[dt][rr * 4 + 0]; sl[1] = o[dt][rr * 4 + 1];
      sl[2] = o[dt][rr * 4 + 2]; sl[3] = o[dt][rr * 4 + 3];
      *(f32x4*)(op + (dt * 4 + rr) * 256 + lane * 4) = sl;
    }
  float2* mlp = ml + ((size_t)pair * 2 + ks) * 128 + wid * 32;
  if (lane < 32) { float2 v2; v2.x = mrun; v2.y = lsum_q; mlp[l31] = v2; }
  __threadfence();                               // device-visible (cross-XCD safe)
  __syncthreads();
  __shared__ int who;
  if (tid == 0) who = atomicAdd(&cnt[pair], 1);
  __syncthreads();
  if (who == 0) return;                          // winner exits; loser merges
  __threadfence();                               // acquire other's stores
  const int os = 1 - ks;
  const float* oq = opart + ((size_t)pair * 2 + os) * 16384 + wid * 4096;
  float2 mlB = (ml + ((size_t)pair * 2 + os) * 128 + wid * 32)[l31];
  // per-r combine factors (q(r) = (r&3)+8*(r>>2)+4*hi)
  float fa[16], fb[16];
#pragma unroll
  for (int r = 0; r < 16; ++r) {
    int src = (r & 3) + 8 * (r >> 2) + 4 * hi;
    float mB = __shfl(mlB.x, src);
    float lB = __shfl(mlB.y, src);
    float mA = __shfl(mrun, src);
    float lA = __shfl(lsum_q, src);
    float M = fmaxf(mA, mB);
    float eA = __builtin_amdgcn_exp2f(mA - M);
    float eB = __builtin_amdgcn_exp2f(mB - M);
    float inv = 1.0f / (lA * eA + lB * eB);
    fa[r] = eA * inv; fb[r] = eB * inv;
  }
#pragma unroll
  for (int dt = 0; dt < 4; ++dt) {
    f32x4 bo[4];
#pragma unroll
    for (int rr = 0; rr < 4; ++rr)
      bo[rr] = *(const f32x4*)(oq + (dt * 4 + rr) * 256 + lane * 4);
#pragma unroll
    for (int r = 0; r < 16; ++r) {
      float val = o[dt][r] * fa[r] + bo[r >> 2][r & 3] * fb[r];
      int qg = q0w + (r & 3) + 8 * (r >> 2) + 4 * hi;
      ao[(size_t)qg * 2048 + h * 128 + dt * 32 + l31] = f2bf(val);
    }
  }
}

// -----------------------------------------------------------------------------
extern "C" void kernel_launch(void* const* d_in, const int* in_sizes, int n_in,
                              void* d_out, int out_size, void* d_ws, size_t ws_size,
                              hipStream_t stream) {
  const float* x    = (const float*)d_in[0];
  const float* wq   = (const float*)d_in[1];
  const float* bq   = (const float*)d_in[2];
  const float* wk   = (const float*)d_in[3];
  const float* bk   = (const float*)d_in[4];
  const float* wv   = (const float*)d_in[5];
  const float* bv   = (const float*)d_in[6];
  const float* wo   = (const float*)d_in[7];
  const float* bo   = (const float*)d_in[8];
  const float* gq   = (const float*)d_in[9];
  const float* gk   = (const float*)d_in[10];
  const float* fcos = (const float*)d_in[11];
  const float* fsin = (const float*)d_in[12];

  // ws layout (92,274,688 B total; lifetime-overlapped):
  //   [0, 25165824)            qkv_pre bf16 (phase A) | opart fp32 (attn)
  //   [33554432, 34078720)     ml float2 (attn)
  //   [34078720, 34079744)     cnt int[256] (attn; zeroed per call)
  //   [50331648, 58720256)     xb bf16 (phase A)   | qb bf16 (phase B+)
  //   [58720256, 83886080)     wqkv bf16 (phase A) | kb, vT, ao bf16 (phase B+)
  //   [83886080, 92274688)     wob bf16 (whole call)
  char* ws = (char*)d_ws;
  u16* qkv_pre = (u16*)ws;                      // 2048 x 6144 bf16 = 25.2 MB
  float* opart = (float*)ws;                    // 512 x 16384 fp32 = 32 MB
  float2* ml   = (float2*)(ws + 33554432);      // 512 x 128 float2 = 512 KB
  int* cnt     = (int*)(ws + 34078720);         // 256 ints
  u16* xb   = (u16*)(ws + 50331648);
  u16* wqkv = (u16*)(ws + 58720256);
  u16* qb   = (u16*)(ws + 50331648);
  u16* kb   = (u16*)(ws + 58720256);
  u16* vT   = (u16*)(ws + 67108864);
  u16* ao   = (u16*)(ws + 75497472);
  u16* wob  = (u16*)(ws + 83886080);

  k_cvt5<<<dim3(4096, 5), 256, 0, stream>>>(x, wq, wk, wv, wo, xb, wqkv, wob);
  k_zero<<<1, 256, 0, stream>>>(cnt);

  // q|k|v = x @ [wq;wk;wv]^T  (bias applied downstream)
  k_gemm_big<<<512, 512, 0, stream>>>(xb, wqkv, qkv_pre, 2048, 6144, 2048);
  k_rmsnorm_rope<<<dim3(2048, 2), 256, 0, stream>>>(qkv_pre, bq, bk, gq, gk,
                                                    fcos, fsin, qb, kb);
  k_transpose_v<<<dim3(32, 32), 256, 0, stream>>>(qkv_pre, bv, vT);
  k_attn<<<512, 256, 0, stream>>>(qb, kb, vT, opart, ml, cnt, ao);
  k_gemm_pipe<<<dim3(512), 256, 0, stream>>>(ao, wob, bo, (float*)d_out,
                                             2048, 2048, 2048);
}

// Round 15
// 156.647 us; speedup vs baseline: 1.5722x; 1.5722x over previous
//
#include <hip/hip_runtime.h>
#include <math.h>

typedef unsigned short u16;
typedef unsigned int u32;
typedef __bf16 bf16x8 __attribute__((ext_vector_type(8)));
typedef float f32x4 __attribute__((ext_vector_type(4)));
typedef float f32x16 __attribute__((ext_vector_type(16)));

__device__ __forceinline__ u16 f2bf(float f) {
  unsigned u = __float_as_uint(f);
  u += 0x7fff + ((u >> 16) & 1);   // RNE
  return (u16)(u >> 16);
}

__device__ __forceinline__ float b2f(u16 x) {
  return __uint_as_float((u32)x << 16);
}

__device__ __forceinline__ u32 cvtpk(float lo, float hi) {
  u32 r;
  asm("v_cvt_pk_bf16_f32 %0, %1, %2" : "=v"(r) : "v"(lo), "v"(hi));
  return r;
}

// v_permlane32_swap_b32 x, y:  x' = [x.lo32lanes, y.lo32lanes],
//                              y' = [x.hi32lanes, y.hi32lanes]
__device__ __forceinline__ void pswap(u32& x, u32& y) {
  asm volatile("v_permlane32_swap_b32 %0, %1" : "+v"(x), "+v"(y));
}

__device__ __forceinline__ void gload_lds16(const void* g, void* l) {
  __builtin_amdgcn_global_load_lds(
      (const __attribute__((address_space(1))) unsigned int*)g,
      (__attribute__((address_space(3))) unsigned int*)l, 16, 0, 0);
}

// ---------------- fp32 -> bf16 convert, 5 x 4M-element tensors in one launch --
__global__ __launch_bounds__(256) void k_cvt5(const float* __restrict__ s0,
                                              const float* __restrict__ s1,
                                              const float* __restrict__ s2,
                                              const float* __restrict__ s3,
                                              const float* __restrict__ s4,
                                              u16* __restrict__ dx,
                                              u16* __restrict__ dqkv,
                                              u16* __restrict__ dwo) {
  const int y = blockIdx.y;
  const float* s = (y == 0) ? s0 : (y == 1) ? s1 : (y == 2) ? s2
                   : (y == 3) ? s3 : s4;
  u16* d = (y == 0) ? dx : (y == 4) ? dwo : dqkv + (size_t)(y - 1) * 4194304;
  int i = (blockIdx.x * 256 + threadIdx.x) * 4;
  float4 v = *(const float4*)(s + i);
  ushort4 o;
  o.x = f2bf(v.x); o.y = f2bf(v.y); o.z = f2bf(v.z); o.w = f2bf(v.w);
  *(ushort4*)(d + i) = o;
}

// ---------------- big GEMM: C[M,N] = A[M,K] * B[N,K]^T, bf16 out ---------------
// 128x192 tile, BK=64, 512 thr (8 waves 2Mx4N, 64x48/wave). Counted-vmcnt
// double-buffered pipeline, raw s_barrier, XOR-swizzled LDS. 80K LDS ->
// 2 blocks/CU; grid 512 -> zero tail. Requires (N/192)%8==0.
__global__ __launch_bounds__(512, 4) void k_gemm_big(const u16* __restrict__ A,
                                                     const u16* __restrict__ B,
                                                     u16* __restrict__ C,
                                                     int M, int N, int K) {
  __shared__ __align__(16) char lds[2][40960];   // per buf: A 16K | B 24K
  const int tid = threadIdx.x;
  const int wid = tid >> 6, lane = tid & 63;
  const int lr = lane & 15, lg = lane >> 4;
  const int wm = (wid >> 2) * 64, wn = (wid & 3) * 48;
  const int nbx = N / 192, nby = M >> 7;
  const int colsPerXcd = nbx >> 3;
  const int xcd = blockIdx.x & 7, idx = blockIdx.x >> 3;
  const int bx = xcd * colsPerXcd + idx / nby;
  const int by = idx % nby;
  const int bm = by * 128, bn = bx * 192;
  const int srow = tid >> 3;                     // 64 rows per issue
  const int schunk = (tid & 7) ^ (srow & 7);     // pre-swizzled 16B chunk
  const size_t rsK = (size_t)K * 2;              // row stride, bytes
  const char* gA = (const char*)A + (size_t)(bm + srow) * rsK + schunk * 16;
  const char* gB = (const char*)B + (size_t)(bn + srow) * rsK + schunk * 16;
  char* dA = (char*)lds + wid * 1024;            // wave-uniform dest bases
  char* dB = (char*)lds + 16384 + wid * 1024;

#define STAGE(cur, k0)                                                         \
  {                                                                            \
    _Pragma("unroll") for (int i = 0; i < 2; ++i)                              \
        gload_lds16(gA + (size_t)(i * 64) * rsK + (size_t)(k0) * 2,            \
                    dA + (cur) * 40960 + i * 8192);                            \
    _Pragma("unroll") for (int i = 0; i < 3; ++i)                              \
        gload_lds16(gB + (size_t)(i * 64) * rsK + (size_t)(k0) * 2,            \
                    dB + (cur) * 40960 + i * 8192);                            \
  }

  f32x4 acc[4][3] = {};
  STAGE(0, 0);
  STAGE(1, 64);
  asm volatile("s_waitcnt vmcnt(5)" ::: "memory");   // tile0 landed
  __builtin_amdgcn_s_barrier();
  const int NT = K >> 6;
  int cur = 0;
  const int rsw = (lr & 7);
  for (int t = 0; t < NT; ++t) {
    const char* La = (const char*)lds + cur * 40960;
    const char* Lb = La + 16384;
    bf16x8 af[4][2], bfr[3][2];
#pragma unroll
    for (int mi = 0; mi < 4; ++mi)
#pragma unroll
      for (int kk = 0; kk < 2; ++kk)
        af[mi][kk] = *(const bf16x8*)(La + (wm + mi * 16 + lr) * 128 +
                                      (((kk * 4 + lg) ^ rsw) * 16));
#pragma unroll
    for (int ni = 0; ni < 3; ++ni)
#pragma unroll
      for (int kk = 0; kk < 2; ++kk)
        bfr[ni][kk] = *(const bf16x8*)(Lb + (wn + ni * 16 + lr) * 128 +
                                       (((kk * 4 + lg) ^ rsw) * 16));
    asm volatile("s_waitcnt lgkmcnt(0)" ::: "memory");
    __builtin_amdgcn_s_barrier();                       // all waves done w/ cur
    if (t + 2 < NT) STAGE(cur, (t + 2) << 6);           // overwrite cur (safe)
    __builtin_amdgcn_s_setprio(1);
#pragma unroll
    for (int kk = 0; kk < 2; ++kk)
#pragma unroll
      for (int mi = 0; mi < 4; ++mi)
#pragma unroll
        for (int ni = 0; ni < 3; ++ni)
          acc[mi][ni] = __builtin_amdgcn_mfma_f32_16x16x32_bf16(
              af[mi][kk], bfr[ni][kk], acc[mi][ni], 0, 0, 0);
    __builtin_amdgcn_s_setprio(0);
    if (t + 2 < NT)
      asm volatile("s_waitcnt vmcnt(5)" ::: "memory");  // t+1 landed, t+2 flying
    else
      asm volatile("s_waitcnt vmcnt(0)" ::: "memory");  // tail: drain
    __builtin_amdgcn_s_barrier();
    cur ^= 1;
  }
#undef STAGE
#pragma unroll
  for (int mi = 0; mi < 4; ++mi)
#pragma unroll
    for (int ni = 0; ni < 3; ++ni)
#pragma unroll
      for (int j = 0; j < 4; ++j)
        C[(size_t)(bm + wm + mi * 16 + lg * 4 + j) * N + bn + wn + ni * 16 + lr] =
            f2bf(acc[mi][ni][j]);
}

// ---------------- pipelined GEMM 128x64 (+bias): final projection -------------
__global__ __launch_bounds__(256, 2) void k_gemm_pipe(const u16* __restrict__ A,
                                                      const u16* __restrict__ B,
                                                      const float* __restrict__ bias,
                                                      float* __restrict__ C,
                                                      int M, int N, int K) {
  __shared__ __align__(16) char lds[2][24576];   // per buf: A 16K | B 8K
  const int tid = threadIdx.x;
  const int wid = tid >> 6, lane = tid & 63;
  const int lr = lane & 15, lg = lane >> 4;
  const int wm = (wid >> 1) * 64, wn = (wid & 1) * 32;
  const int nbx = N >> 6, nby = M >> 7;
  const int colsPerXcd = nbx >> 3;
  const int xcd = blockIdx.x & 7, idx = blockIdx.x >> 3;
  const int bx = xcd * colsPerXcd + idx / nby;
  const int by = idx % nby;
  const int bm = by * 128, bn = bx * 64;
  const int srow = tid >> 3;                     // 32 rows per issue
  const int schunk = (tid & 7) ^ (srow & 7);
  const size_t rsK = (size_t)K * 2;
  const char* gA = (const char*)A + (size_t)(bm + srow) * rsK + schunk * 16;
  const char* gB = (const char*)B + (size_t)(bn + srow) * rsK + schunk * 16;
  char* dA = (char*)lds + wid * 1024;
  char* dB = (char*)lds + 16384 + wid * 1024;

#define STAGE(cur, k0)                                                         \
  {                                                                            \
    _Pragma("unroll") for (int i = 0; i < 4; ++i)                              \
        gload_lds16(gA + (size_t)(i * 32) * rsK + (size_t)(k0) * 2,            \
                    dA + (cur) * 24576 + i * 4096);                            \
    _Pragma("unroll") for (int i = 0; i < 2; ++i)                              \
        gload_lds16(gB + (size_t)(i * 32) * rsK + (size_t)(k0) * 2,            \
                    dB + (cur) * 24576 + i * 4096);                            \
  }

  f32x4 acc[4][2] = {};
  STAGE(0, 0);
  STAGE(1, 64);
  asm volatile("s_waitcnt vmcnt(6)" ::: "memory");   // tile0 landed
  __builtin_amdgcn_s_barrier();
  const int NT = K >> 6;
  int cur = 0;
  const int rsw = (lr & 7);
  for (int t = 0; t < NT; ++t) {
    const char* La = (const char*)lds + cur * 24576;
    const char* Lb = La + 16384;
    bf16x8 af[4][2], bfr[2][2];
#pragma unroll
    for (int mi = 0; mi < 4; ++mi)
#pragma unroll
      for (int kk = 0; kk < 2; ++kk)
        af[mi][kk] = *(const bf16x8*)(La + (wm + mi * 16 + lr) * 128 +
                                      (((kk * 4 + lg) ^ rsw) * 16));
#pragma unroll
    for (int ni = 0; ni < 2; ++ni)
#pragma unroll
      for (int kk = 0; kk < 2; ++kk)
        bfr[ni][kk] = *(const bf16x8*)(Lb + (wn + ni * 16 + lr) * 128 +
                                       (((kk * 4 + lg) ^ rsw) * 16));
    asm volatile("s_waitcnt lgkmcnt(0)" ::: "memory");
    __builtin_amdgcn_s_barrier();
    if (t + 2 < NT) STAGE(cur, (t + 2) << 6);
    __builtin_amdgcn_s_setprio(1);
#pragma unroll
    for (int kk = 0; kk < 2; ++kk)
#pragma unroll
      for (int mi = 0; mi < 4; ++mi)
#pragma unroll
        for (int ni = 0; ni < 2; ++ni)
          acc[mi][ni] = __builtin_amdgcn_mfma_f32_16x16x32_bf16(
              af[mi][kk], bfr[ni][kk], acc[mi][ni], 0, 0, 0);
    __builtin_amdgcn_s_setprio(0);
    if (t + 2 < NT)
      asm volatile("s_waitcnt vmcnt(6)" ::: "memory");
    else
      asm volatile("s_waitcnt vmcnt(0)" ::: "memory");
    __builtin_amdgcn_s_barrier();
    cur ^= 1;
  }
#undef STAGE
#pragma unroll
  for (int mi = 0; mi < 4; ++mi)
#pragma unroll
    for (int ni = 0; ni < 2; ++ni) {
      int col = bn + wn + ni * 16 + lr;
      float bb = bias[col];
#pragma unroll
      for (int j = 0; j < 4; ++j)
        C[(size_t)(bm + wm + mi * 16 + lg * 4 + j) * N + col] =
            acc[mi][ni][j] + bb;
    }
}

// ---------------- RMSNorm(+bias) + RoPE, bf16 in -> bf16 out -----------------
// q additionally pre-scaled by 1/sqrt(HD) * log2(e)  (attention uses exp2)
__global__ __launch_bounds__(256) void k_rmsnorm_rope(
    const u16* __restrict__ qkv, const float* __restrict__ bq,
    const float* __restrict__ bk, const float* __restrict__ gq,
    const float* __restrict__ gk, const float* __restrict__ fcos,
    const float* __restrict__ fsin, u16* __restrict__ qb, u16* __restrict__ kb) {
  const int s = blockIdx.x, which = blockIdx.y;
  const int t = threadIdx.x;
  const u16* src = qkv + (size_t)s * 6144 + which * 2048;
  const float* bias = which ? bk : bq;
  const float* g = which ? gk : gq;
  u16* dst = (which ? kb : qb) + (size_t)s * 2048;
  const int c0 = t * 8;
  uint4 raw = *(const uint4*)(src + c0);         // 8 bf16
  const u16* rp = (const u16*)&raw;
  float4 b0 = *(const float4*)(bias + c0);
  float4 b1 = *(const float4*)(bias + c0 + 4);
  float v[8];
  v[0] = b2f(rp[0]) + b0.x; v[1] = b2f(rp[1]) + b0.y;
  v[2] = b2f(rp[2]) + b0.z; v[3] = b2f(rp[3]) + b0.w;
  v[4] = b2f(rp[4]) + b1.x; v[5] = b2f(rp[5]) + b1.y;
  v[6] = b2f(rp[6]) + b1.z; v[7] = b2f(rp[7]) + b1.w;
  float ss = 0.f;
#pragma unroll
  for (int j = 0; j < 8; ++j) ss += v[j] * v[j];
#pragma unroll
  for (int m = 1; m < 64; m <<= 1) ss += __shfl_xor(ss, m);
  __shared__ float red[4];
  if ((t & 63) == 0) red[t >> 6] = ss;
  __syncthreads();
  float r = rsqrtf((red[0] + red[1] + red[2] + red[3]) * (1.0f / 2048.0f) + 1e-6f);
  if (!which) r *= 0.08838834764831843f * 1.4426950408889634f;
  float4 g0 = *(const float4*)(g + c0);
  float4 g1 = *(const float4*)(g + c0 + 4);
  float gg[8] = {g0.x, g0.y, g0.z, g0.w, g1.x, g1.y, g1.z, g1.w};
  const int p0 = (c0 & 127) >> 1;
  u16 o[8];
#pragma unroll
  for (int j = 0; j < 4; ++j) {
    float a = v[2 * j] * r * gg[2 * j];
    float b = v[2 * j + 1] * r * gg[2 * j + 1];
    float co = fcos[s * 64 + p0 + j], si = fsin[s * 64 + p0 + j];
    o[2 * j]     = f2bf(a * co - b * si);
    o[2 * j + 1] = f2bf(a * si + b * co);
  }
  ushort4 q0; q0.x = o[0]; q0.y = o[1]; q0.z = o[2]; q0.w = o[3];
  ushort4 q1; q1.x = o[4]; q1.y = o[5]; q1.z = o[6]; q1.w = o[7];
  *(ushort4*)(dst + c0) = q0;
  *(ushort4*)(dst + c0 + 4) = q1;
}

// ---------------- V: bias + transpose -> vT[h*128+d][s] bf16 -----------------
__global__ __launch_bounds__(256) void k_transpose_v(const u16* __restrict__ qkv,
                                                     const float* __restrict__ bv,
                                                     u16* __restrict__ vT) {
  __shared__ float tile[64][65];
  const int s0 = blockIdx.x * 64, d0 = blockIdx.y * 64;
  const int t = threadIdx.x;
  const int tc = (t & 15) * 4, tr = t >> 4;
  float4 bb = *(const float4*)(bv + d0 + tc);
#pragma unroll
  for (int i = 0; i < 4; ++i) {
    int sr = tr + i * 16;
    ushort4 x = *(const ushort4*)(qkv + (size_t)(s0 + sr) * 6144 + 4096 + d0 + tc);
    tile[sr][tc + 0] = b2f(x.x) + bb.x;
    tile[sr][tc + 1] = b2f(x.y) + bb.y;
    tile[sr][tc + 2] = b2f(x.z) + bb.z;
    tile[sr][tc + 3] = b2f(x.w) + bb.w;
  }
  __syncthreads();
#pragma unroll
  for (int i = 0; i < 4; ++i) {
    int dr = tr + i * 16;
    ushort4 o;
    o.x = f2bf(tile[tc + 0][dr]);
    o.y = f2bf(tile[tc + 1][dr]);
    o.z = f2bf(tile[tc + 2][dr]);
    o.w = f2bf(tile[tc + 3][dr]);
    *(ushort4*)(vT + (size_t)(d0 + dr) * 2048 + s0 + tc) = o;
  }
}

// ---------------- flash attention: swapped QK^T, in-register softmax ----------
// flat grid 512, decode: xcd (bid&7) owns heads {2x,2x+1} -> K/V/Q L2-resident.
// 4 waves x 32 q-rows, 32x32x16 MFMA. K,V double-buffered, r10 schedule.
// lsum computed on the MATRIX pipe: o4 += mfma(pa[s], ones) accumulates the
// row-sum of P (V==1), removing the per-tile sum tree + shfl from the VALU
// stream. Defer-rescale multiplies o4 along with o. Epilogue extracts
// lsum[q] from o4 via unrolled cndmask select (static idx) + one shfl.
__global__ __launch_bounds__(256, 2) void k_attn(const u16* __restrict__ qb,
                                                 const u16* __restrict__ kb,
                                                 const u16* __restrict__ vT,
                                                 float* __restrict__ opart,
                                                 float* __restrict__ ml) {
  __shared__ __align__(16) char Ks[2][16384];    // K tile [64 keys][128 d]
  __shared__ __align__(16) char Vs[2][16384];    // V tile [128 d][64 k]
  const int bid = blockIdx.x;
  const int xcd = bid & 7, j = bid >> 3;         // j in 0..63
  const int h = xcd * 2 + (j & 1);
  const int qt = (j >> 1) & 15;
  const int ks = j >> 5;
  const int tid = threadIdx.x;
  const int wid = tid >> 6, lane = tid & 63;
  const int l31 = lane & 31, hi = lane >> 5;
  const int q0w = qt * 128 + wid * 32;
  const char* kbB = (const char*)kb;
  const char* vTB = (const char*)vT;
  const int krow = tid >> 4;                     // K: 16 rows/issue, 256B rows
  const int kc = (tid & 15) ^ krow;              // 4-bit XOR (16 chunks/row)
  const int vrow = tid >> 3;                     // V: 32 rows/issue, 128B rows
  const int vc = (tid & 7) ^ (vrow & 7);         // 3-bit XOR (8 chunks/row)

#define STAGE(buf, k0)                                                         \
  {                                                                            \
    _Pragma("unroll") for (int i = 0; i < 4; ++i)                              \
        gload_lds16(kbB + (size_t)((k0) + i * 16 + krow) * 4096 + h * 256 +    \
                        kc * 16,                                               \
                    (char*)Ks + (buf) * 16384 + i * 4096 + wid * 1024);        \
    _Pragma("unroll") for (int i = 0; i < 4; ++i)                              \
        gload_lds16(vTB + (size_t)(h * 128 + i * 32 + vrow) * 4096 +           \
                        (size_t)(k0) * 2 + vc * 16,                            \
                    (char*)Vs + (buf) * 16384 + i * 4096 + wid * 1024);        \
  }

  // Q fragments: B-operand, col q = l31, d-elems = ds*16 + hi*8 .. +8
  bf16x8 qf[8];
#pragma unroll
  for (int ds = 0; ds < 8; ++ds)
    qf[ds] = *(const bf16x8*)(qb + (size_t)(q0w + l31) * 2048 + h * 128 +
                              ds * 16 + hi * 8);
  f32x16 o[4] = {};                              // O[q reg-mapped][dt*32+l31]
  f32x16 o4 = {};                                // row-sum accumulator (V==1)
  float mrun = -3.0e38f;
  const int kbeg = ks * 1024;
  const int ksw = l31 & 15, vsw = l31 & 7;       // read-side swizzle keys
  union { u32 w[4]; bf16x8 v; } onesu;
  onesu.w[0] = 0x3F803F80u; onesu.w[1] = 0x3F803F80u;
  onesu.w[2] = 0x3F803F80u; onesu.w[3] = 0x3F803F80u;
  const bf16x8 vones = onesu.v;
  STAGE(0, kbeg);
  __syncthreads();
  int cur = 0;
  for (int t = 0; t < 16; ++t) {
    if (t + 1 < 16) STAGE(cur ^ 1, kbeg + (t + 1) * 64);
    const char* Kc = Ks[cur];
    const char* Vc = Vs[cur];
    // QK^T swapped: p[h2] = K[h2*32..+32) x Q  -> D[k][q]
    f32x16 p0 = {}, p1 = {};
    __builtin_amdgcn_s_setprio(1);
#pragma unroll
    for (int ds = 0; ds < 8; ++ds) {
      bf16x8 kf0 = *(const bf16x8*)(Kc + l31 * 256 + (((ds * 2 + hi) ^ ksw) * 16));
      p0 = __builtin_amdgcn_mfma_f32_32x32x16_bf16(kf0, qf[ds], p0, 0, 0, 0);
      bf16x8 kf1 = *(const bf16x8*)(Kc + (32 + l31) * 256 +
                                    (((ds * 2 + hi) ^ ksw) * 16));
      p1 = __builtin_amdgcn_mfma_f32_32x32x16_bf16(kf1, qf[ds], p1, 0, 0, 0);
    }
    __builtin_amdgcn_s_setprio(0);
    // row max: pairwise tree, depth 5
    {
      float tm[8];
#pragma unroll
      for (int r = 0; r < 8; ++r)
        tm[r] = fmaxf(fmaxf(p0[2 * r], p0[2 * r + 1]),
                      fmaxf(p1[2 * r], p1[2 * r + 1]));
#pragma unroll
      for (int s = 4; s > 0; s >>= 1)
#pragma unroll
        for (int r = 0; r < s; ++r) tm[r] = fmaxf(tm[r], tm[r + s]);
      float pm = fmaxf(tm[0], __shfl_xor(tm[0], 32));
      // T13 defer-rescale (log2 domain, THR=8 -> P bounded by 2^8)
      if (!__all(pm <= mrun + 8.0f)) {
        float nm = fmaxf(mrun, pm);
        float fv = __builtin_amdgcn_exp2f(mrun - nm);
#pragma unroll
        for (int dt = 0; dt < 4; ++dt) o[dt] *= fv;
        o4 *= fv;
        mrun = nm;
      }
    }
#pragma unroll
    for (int r = 0; r < 16; ++r) p0[r] = __builtin_amdgcn_exp2f(p0[r] - mrun);
#pragma unroll
    for (int r = 0; r < 16; ++r) p1[r] = __builtin_amdgcn_exp2f(p1[r] - mrun);
    // P -> PA fragments via cvt_pk + permlane32_swap (no LDS roundtrip)
    bf16x8 pa[4];
#pragma unroll
    for (int sl = 0; sl < 2; ++sl) {
      u32 E0 = cvtpk(p0[8 * sl + 0], p0[8 * sl + 1]);
      u32 E1 = cvtpk(p0[8 * sl + 2], p0[8 * sl + 3]);
      u32 O0 = cvtpk(p0[8 * sl + 4], p0[8 * sl + 5]);
      u32 O1 = cvtpk(p0[8 * sl + 6], p0[8 * sl + 7]);
      pswap(E0, O0); pswap(E1, O1);
      union { u32 w[4]; bf16x8 v; } uu;
      uu.w[0] = E0; uu.w[1] = E1; uu.w[2] = O0; uu.w[3] = O1;
      pa[sl] = uu.v;
    }
#pragma unroll
    for (int sl = 0; sl < 2; ++sl) {
      u32 E0 = cvtpk(p1[8 * sl + 0], p1[8 * sl + 1]);
      u32 E1 = cvtpk(p1[8 * sl + 2], p1[8 * sl + 3]);
      u32 O0 = cvtpk(p1[8 * sl + 4], p1[8 * sl + 5]);
      u32 O1 = cvtpk(p1[8 * sl + 6], p1[8 * sl + 7]);
      pswap(E0, O0); pswap(E1, O1);
      union { u32 w[4]; bf16x8 v; } uu;
      uu.w[0] = E0; uu.w[1] = E1; uu.w[2] = O0; uu.w[3] = O1;
      pa[2 + sl] = uu.v;
    }
    // PV: O[q][d] += PA[q][16k] x V[16k][32d]; o4 += PA x ones (row-sum)
    __builtin_amdgcn_s_setprio(1);
#pragma unroll
    for (int s = 0; s < 4; ++s) {
#pragma unroll
      for (int dt = 0; dt < 4; ++dt) {
        bf16x8 vf = *(const bf16x8*)(Vc + (dt * 32 + l31) * 128 +
                                     (((s * 2 + hi) ^ vsw) * 16));
        o[dt] = __builtin_amdgcn_mfma_f32_32x32x16_bf16(pa[s], vf, o[dt], 0, 0, 0);
      }
      o4 = __builtin_amdgcn_mfma_f32_32x32x16_bf16(pa[s], vones, o4, 0, 0, 0);
    }
    __builtin_amdgcn_s_setprio(0);
    __syncthreads();                             // stage done + bufs consumed
    cur ^= 1;
  }
#undef STAGE
  // write unnormalized partials; q_row(r) = (r&3) + 8*(r>>2) + 4*hi
  float* opb = opart + ((size_t)ks * 32768 + (size_t)h * 2048 + q0w) * 128 + l31;
#pragma unroll
  for (int dt = 0; dt < 4; ++dt)
#pragma unroll
    for (int r = 0; r < 16; ++r)
      opb[(size_t)((r & 3) + 8 * (r >> 2) + 4 * hi) * 128 + dt * 32] = o[dt][r];
  // lsum for q = l31 lives in o4[rsel] of the lane-half with hi == (q>>2)&1
  {
    const int rsel = (l31 & 3) | (((l31 >> 3) & 3) << 2);
    float cand = o4[0];
#pragma unroll
    for (int r = 1; r < 16; ++r) cand = (rsel == r) ? o4[r] : cand;
    float other = __shfl_xor(cand, 32);
    float lsum_q = (hi == ((l31 >> 2) & 1)) ? cand : other;
    if (lane < 32) {
      float2 v2; v2.x = mrun; v2.y = lsum_q;
      *(float2*)(ml + ((size_t)ks * 32768 + (size_t)h * 2048 + q0w + l31) * 2) = v2;
    }
  }
}

// ---------------- merge 2 k-split partials -> ao bf16 [s][h*128+d] -----------
__global__ __launch_bounds__(256) void k_attn_merge(const float* __restrict__ opart,
                                                    const float* __restrict__ ml,
                                                    u16* __restrict__ ob) {
  const int r = blockIdx.x * 8 + (threadIdx.x >> 5);   // r = h*2048 + q
  const int d0 = (threadIdx.x & 31) * 4;
  float2 ml0 = *(const float2*)(ml + (size_t)r * 2);
  float2 ml1 = *(const float2*)(ml + (size_t)(32768 + r) * 2);
  float M = fmaxf(ml0.x, ml1.x);
  float f0 = __builtin_amdgcn_exp2f(ml0.x - M);
  float f1 = __builtin_amdgcn_exp2f(ml1.x - M);
  float inv = 1.0f / (ml0.y * f0 + ml1.y * f1);
  float4 a = *(const float4*)(opart + (size_t)r * 128 + d0);
  float4 b = *(const float4*)(opart + (size_t)(32768 + r) * 128 + d0);
  int h = r >> 11, q = r & 2047;
  ushort4 o;
  o.x = f2bf((a.x * f0 + b.x * f1) * inv);
  o.y = f2bf((a.y * f0 + b.y * f1) * inv);
  o.z = f2bf((a.z * f0 + b.z * f1) * inv);
  o.w = f2bf((a.w * f0 + b.w * f1) * inv);
  *(ushort4*)(ob + (size_t)q * 2048 + h * 128 + d0) = o;
}

// -----------------------------------------------------------------------------
extern "C" void kernel_launch(void* const* d_in, const int* in_sizes, int n_in,
                              void* d_out, int out_size, void* d_ws, size_t ws_size,
                              hipStream_t stream) {
  const float* x    = (const float*)d_in[0];
  const float* wq   = (const float*)d_in[1];
  const float* bq   = (const float*)d_in[2];
  const float* wk   = (const float*)d_in[3];
  const float* bk   = (const float*)d_in[4];
  const float* wv   = (const float*)d_in[5];
  const float* bv   = (const float*)d_in[6];
  const float* wo   = (const float*)d_in[7];
  const float* bo   = (const float*)d_in[8];
  const float* gq   = (const float*)d_in[9];
  const float* gk   = (const float*)d_in[10];
  const float* fcos = (const float*)d_in[11];
  const float* fsin = (const float*)d_in[12];

  // ws layout (92,274,688 B total; lifetime-overlapped):
  //   [0, 25165824)            qkv_pre bf16 (phase A) | opart+ml (attn phase)
  //   [50331648, 58720256)     xb bf16 (phase A)   | qb bf16 (phase B+)
  //   [58720256, 83886080)     wqkv bf16 (phase A) | kb, vT, ao bf16 (phase B+)
  //   [83886080, 92274688)     wob bf16 (whole call)
  char* ws = (char*)d_ws;
  u16* qkv_pre = (u16*)ws;                      // 2048 x 6144 bf16 = 25.2 MB
  float* opart = (float*)ws;                    // 2 x 32768 x 128 fp32 = 32 MB
  float* ml    = (float*)(ws + 33554432);       // 2 x 32768 x 2 fp32 = 512 KB
  u16* xb   = (u16*)(ws + 50331648);
  u16* wqkv = (u16*)(ws + 58720256);
  u16* qb   = (u16*)(ws + 50331648);
  u16* kb   = (u16*)(ws + 58720256);
  u16* vT   = (u16*)(ws + 67108864);
  u16* ao   = (u16*)(ws + 75497472);
  u16* wob  = (u16*)(ws + 83886080);

  k_cvt5<<<dim3(4096, 5), 256, 0, stream>>>(x, wq, wk, wv, wo, xb, wqkv, wob);

  // q|k|v = x @ [wq;wk;wv]^T  (bias applied downstream)
  k_gemm_big<<<512, 512, 0, stream>>>(xb, wqkv, qkv_pre, 2048, 6144, 2048);
  k_rmsnorm_rope<<<dim3(2048, 2), 256, 0, stream>>>(qkv_pre, bq, bk, gq, gk,
                                                    fcos, fsin, qb, kb);
  k_transpose_v<<<dim3(32, 32), 256, 0, stream>>>(qkv_pre, bv, vT);
  k_attn<<<512, 256, 0, stream>>>(qb, kb, vT, opart, ml);
  k_attn_merge<<<4096, 256, 0, stream>>>(opart, ml, ao);
  k_gemm_pipe<<<dim3(512), 256, 0, stream>>>(ao, wob, bo, (float*)d_out,
                                             2048, 2048, 2048);
}

// Round 16
// 154.504 us; speedup vs baseline: 1.5940x; 1.0139x over previous
//
#include <hip/hip_runtime.h>
#include <math.h>

typedef unsigned short u16;
typedef unsigned int u32;
typedef __bf16 bf16x8 __attribute__((ext_vector_type(8)));
typedef float f32x4 __attribute__((ext_vector_type(4)));
typedef float f32x16 __attribute__((ext_vector_type(16)));

__device__ __forceinline__ u16 f2bf(float f) {
  unsigned u = __float_as_uint(f);
  u += 0x7fff + ((u >> 16) & 1);   // RNE
  return (u16)(u >> 16);
}

__device__ __forceinline__ float b2f(u16 x) {
  return __uint_as_float((u32)x << 16);
}

__device__ __forceinline__ u32 cvtpk(float lo, float hi) {
  u32 r;
  asm("v_cvt_pk_bf16_f32 %0, %1, %2" : "=v"(r) : "v"(lo), "v"(hi));
  return r;
}

// v_permlane32_swap_b32 x, y:  x' = [x.lo32lanes, y.lo32lanes],
//                              y' = [x.hi32lanes, y.hi32lanes]
__device__ __forceinline__ void pswap(u32& x, u32& y) {
  asm volatile("v_permlane32_swap_b32 %0, %1" : "+v"(x), "+v"(y));
}

__device__ __forceinline__ void gload_lds16(const void* g, void* l) {
  __builtin_amdgcn_global_load_lds(
      (const __attribute__((address_space(1))) unsigned int*)g,
      (__attribute__((address_space(3))) unsigned int*)l, 16, 0, 0);
}

// ---------------- fp32 -> bf16 convert, 5 x 4M-element tensors in one launch --
__global__ __launch_bounds__(256) void k_cvt5(const float* __restrict__ s0,
                                              const float* __restrict__ s1,
                                              const float* __restrict__ s2,
                                              const float* __restrict__ s3,
                                              const float* __restrict__ s4,
                                              u16* __restrict__ dx,
                                              u16* __restrict__ dqkv,
                                              u16* __restrict__ dwo) {
  const int y = blockIdx.y;
  const float* s = (y == 0) ? s0 : (y == 1) ? s1 : (y == 2) ? s2
                   : (y == 3) ? s3 : s4;
  u16* d = (y == 0) ? dx : (y == 4) ? dwo : dqkv + (size_t)(y - 1) * 4194304;
  int i = (blockIdx.x * 256 + threadIdx.x) * 4;
  float4 v = *(const float4*)(s + i);
  ushort4 o;
  o.x = f2bf(v.x); o.y = f2bf(v.y); o.z = f2bf(v.z); o.w = f2bf(v.w);
  *(ushort4*)(d + i) = o;
}

// ---------------- big GEMM: C[M,N] = A[M,K] * B[N,K]^T, bf16 out ---------------
// 128x192 tile, BK=64, 512 thr (8 waves 2Mx4N, 64x48/wave). Counted-vmcnt
// double-buffered pipeline, raw s_barrier, XOR-swizzled LDS. 80K LDS ->
// 2 blocks/CU; grid 512 -> zero tail. Requires (N/192)%8==0.
__global__ __launch_bounds__(512, 4) void k_gemm_big(const u16* __restrict__ A,
                                                     const u16* __restrict__ B,
                                                     u16* __restrict__ C,
                                                     int M, int N, int K) {
  __shared__ __align__(16) char lds[2][40960];   // per buf: A 16K | B 24K
  const int tid = threadIdx.x;
  const int wid = tid >> 6, lane = tid & 63;
  const int lr = lane & 15, lg = lane >> 4;
  const int wm = (wid >> 2) * 64, wn = (wid & 3) * 48;
  const int nbx = N / 192, nby = M >> 7;
  const int colsPerXcd = nbx >> 3;
  const int xcd = blockIdx.x & 7, idx = blockIdx.x >> 3;
  const int bx = xcd * colsPerXcd + idx / nby;
  const int by = idx % nby;
  const int bm = by * 128, bn = bx * 192;
  const int srow = tid >> 3;                     // 64 rows per issue
  const int schunk = (tid & 7) ^ (srow & 7);     // pre-swizzled 16B chunk
  const size_t rsK = (size_t)K * 2;              // row stride, bytes
  const char* gA = (const char*)A + (size_t)(bm + srow) * rsK + schunk * 16;
  const char* gB = (const char*)B + (size_t)(bn + srow) * rsK + schunk * 16;
  char* dA = (char*)lds + wid * 1024;            // wave-uniform dest bases
  char* dB = (char*)lds + 16384 + wid * 1024;

#define STAGE(cur, k0)                                                         \
  {                                                                            \
    _Pragma("unroll") for (int i = 0; i < 2; ++i)                              \
        gload_lds16(gA + (size_t)(i * 64) * rsK + (size_t)(k0) * 2,            \
                    dA + (cur) * 40960 + i * 8192);                            \
    _Pragma("unroll") for (int i = 0; i < 3; ++i)                              \
        gload_lds16(gB + (size_t)(i * 64) * rsK + (size_t)(k0) * 2,            \
                    dB + (cur) * 40960 + i * 8192);                            \
  }

  f32x4 acc[4][3] = {};
  STAGE(0, 0);
  STAGE(1, 64);
  asm volatile("s_waitcnt vmcnt(5)" ::: "memory");   // tile0 landed
  __builtin_amdgcn_s_barrier();
  const int NT = K >> 6;
  int cur = 0;
  const int rsw = (lr & 7);
  for (int t = 0; t < NT; ++t) {
    const char* La = (const char*)lds + cur * 40960;
    const char* Lb = La + 16384;
    bf16x8 af[4][2], bfr[3][2];
#pragma unroll
    for (int mi = 0; mi < 4; ++mi)
#pragma unroll
      for (int kk = 0; kk < 2; ++kk)
        af[mi][kk] = *(const bf16x8*)(La + (wm + mi * 16 + lr) * 128 +
                                      (((kk * 4 + lg) ^ rsw) * 16));
#pragma unroll
    for (int ni = 0; ni < 3; ++ni)
#pragma unroll
      for (int kk = 0; kk < 2; ++kk)
        bfr[ni][kk] = *(const bf16x8*)(Lb + (wn + ni * 16 + lr) * 128 +
                                       (((kk * 4 + lg) ^ rsw) * 16));
    asm volatile("s_waitcnt lgkmcnt(0)" ::: "memory");
    __builtin_amdgcn_s_barrier();                       // all waves done w/ cur
    if (t + 2 < NT) STAGE(cur, (t + 2) << 6);           // overwrite cur (safe)
    __builtin_amdgcn_s_setprio(1);
#pragma unroll
    for (int kk = 0; kk < 2; ++kk)
#pragma unroll
      for (int mi = 0; mi < 4; ++mi)
#pragma unroll
        for (int ni = 0; ni < 3; ++ni)
          acc[mi][ni] = __builtin_amdgcn_mfma_f32_16x16x32_bf16(
              af[mi][kk], bfr[ni][kk], acc[mi][ni], 0, 0, 0);
    __builtin_amdgcn_s_setprio(0);
    if (t + 2 < NT)
      asm volatile("s_waitcnt vmcnt(5)" ::: "memory");  // t+1 landed, t+2 flying
    else
      asm volatile("s_waitcnt vmcnt(0)" ::: "memory");  // tail: drain
    __builtin_amdgcn_s_barrier();
    cur ^= 1;
  }
#undef STAGE
#pragma unroll
  for (int mi = 0; mi < 4; ++mi)
#pragma unroll
    for (int ni = 0; ni < 3; ++ni)
#pragma unroll
      for (int j = 0; j < 4; ++j)
        C[(size_t)(bm + wm + mi * 16 + lg * 4 + j) * N + bn + wn + ni * 16 + lr] =
            f2bf(acc[mi][ni][j]);
}

// ---------------- pipelined GEMM 128x64 (+bias): final projection -------------
__global__ __launch_bounds__(256, 2) void k_gemm_pipe(const u16* __restrict__ A,
                                                      const u16* __restrict__ B,
                                                      const float* __restrict__ bias,
                                                      float* __restrict__ C,
                                                      int M, int N, int K) {
  __shared__ __align__(16) char lds[2][24576];   // per buf: A 16K | B 8K
  const int tid = threadIdx.x;
  const int wid = tid >> 6, lane = tid & 63;
  const int lr = lane & 15, lg = lane >> 4;
  const int wm = (wid >> 1) * 64, wn = (wid & 1) * 32;
  const int nbx = N >> 6, nby = M >> 7;
  const int colsPerXcd = nbx >> 3;
  const int xcd = blockIdx.x & 7, idx = blockIdx.x >> 3;
  const int bx = xcd * colsPerXcd + idx / nby;
  const int by = idx % nby;
  const int bm = by * 128, bn = bx * 64;
  const int srow = tid >> 3;                     // 32 rows per issue
  const int schunk = (tid & 7) ^ (srow & 7);
  const size_t rsK = (size_t)K * 2;
  const char* gA = (const char*)A + (size_t)(bm + srow) * rsK + schunk * 16;
  const char* gB = (const char*)B + (size_t)(bn + srow) * rsK + schunk * 16;
  char* dA = (char*)lds + wid * 1024;
  char* dB = (char*)lds + 16384 + wid * 1024;

#define STAGE(cur, k0)                                                         \
  {                                                                            \
    _Pragma("unroll") for (int i = 0; i < 4; ++i)                              \
        gload_lds16(gA + (size_t)(i * 32) * rsK + (size_t)(k0) * 2,            \
                    dA + (cur) * 24576 + i * 4096);                            \
    _Pragma("unroll") for (int i = 0; i < 2; ++i)                              \
        gload_lds16(gB + (size_t)(i * 32) * rsK + (size_t)(k0) * 2,            \
                    dB + (cur) * 24576 + i * 4096);                            \
  }

  f32x4 acc[4][2] = {};
  STAGE(0, 0);
  STAGE(1, 64);
  asm volatile("s_waitcnt vmcnt(6)" ::: "memory");   // tile0 landed
  __builtin_amdgcn_s_barrier();
  const int NT = K >> 6;
  int cur = 0;
  const int rsw = (lr & 7);
  for (int t = 0; t < NT; ++t) {
    const char* La = (const char*)lds + cur * 24576;
    const char* Lb = La + 16384;
    bf16x8 af[4][2], bfr[2][2];
#pragma unroll
    for (int mi = 0; mi < 4; ++mi)
#pragma unroll
      for (int kk = 0; kk < 2; ++kk)
        af[mi][kk] = *(const bf16x8*)(La + (wm + mi * 16 + lr) * 128 +
                                      (((kk * 4 + lg) ^ rsw) * 16));
#pragma unroll
    for (int ni = 0; ni < 2; ++ni)
#pragma unroll
      for (int kk = 0; kk < 2; ++kk)
        bfr[ni][kk] = *(const bf16x8*)(Lb + (wn + ni * 16 + lr) * 128 +
                                       (((kk * 4 + lg) ^ rsw) * 16));
    asm volatile("s_waitcnt lgkmcnt(0)" ::: "memory");
    __builtin_amdgcn_s_barrier();
    if (t + 2 < NT) STAGE(cur, (t + 2) << 6);
    __builtin_amdgcn_s_setprio(1);
#pragma unroll
    for (int kk = 0; kk < 2; ++kk)
#pragma unroll
      for (int mi = 0; mi < 4; ++mi)
#pragma unroll
        for (int ni = 0; ni < 2; ++ni)
          acc[mi][ni] = __builtin_amdgcn_mfma_f32_16x16x32_bf16(
              af[mi][kk], bfr[ni][kk], acc[mi][ni], 0, 0, 0);
    __builtin_amdgcn_s_setprio(0);
    if (t + 2 < NT)
      asm volatile("s_waitcnt vmcnt(6)" ::: "memory");
    else
      asm volatile("s_waitcnt vmcnt(0)" ::: "memory");
    __builtin_amdgcn_s_barrier();
    cur ^= 1;
  }
#undef STAGE
#pragma unroll
  for (int mi = 0; mi < 4; ++mi)
#pragma unroll
    for (int ni = 0; ni < 2; ++ni) {
      int col = bn + wn + ni * 16 + lr;
      float bb = bias[col];
#pragma unroll
      for (int j = 0; j < 4; ++j)
        C[(size_t)(bm + wm + mi * 16 + lg * 4 + j) * N + col] =
            acc[mi][ni][j] + bb;
    }
}

// ---------------- fused prep: RMSNorm+RoPE (y<2) | V bias+transpose (y==2) ----
// y=0: q rows (pre-scaled by 1/sqrt(HD)*log2e), y=1: k rows,
// y=2: blockIdx.x<1024 -> 64x64 V transpose tiles (s0=(bx&31)*64, d0=(bx>>5)*64)
__global__ __launch_bounds__(256) void k_prep(
    const u16* __restrict__ qkv, const float* __restrict__ bq,
    const float* __restrict__ bk, const float* __restrict__ bv,
    const float* __restrict__ gq, const float* __restrict__ gk,
    const float* __restrict__ fcos, const float* __restrict__ fsin,
    u16* __restrict__ qb, u16* __restrict__ kb, u16* __restrict__ vT) {
  const int which = blockIdx.y;
  const int t = threadIdx.x;
  if (which == 2) {
    // ---- V transpose path ----
    const int bx = blockIdx.x;
    if (bx >= 1024) return;
    __shared__ float tile[64][65];
    const int s0 = (bx & 31) * 64, d0 = (bx >> 5) * 64;
    const int tc = (t & 15) * 4, tr = t >> 4;
    float4 bb = *(const float4*)(bv + d0 + tc);
#pragma unroll
    for (int i = 0; i < 4; ++i) {
      int sr = tr + i * 16;
      ushort4 x = *(const ushort4*)(qkv + (size_t)(s0 + sr) * 6144 + 4096 + d0 + tc);
      tile[sr][tc + 0] = b2f(x.x) + bb.x;
      tile[sr][tc + 1] = b2f(x.y) + bb.y;
      tile[sr][tc + 2] = b2f(x.z) + bb.z;
      tile[sr][tc + 3] = b2f(x.w) + bb.w;
    }
    __syncthreads();
#pragma unroll
    for (int i = 0; i < 4; ++i) {
      int dr = tr + i * 16;
      ushort4 o;
      o.x = f2bf(tile[tc + 0][dr]);
      o.y = f2bf(tile[tc + 1][dr]);
      o.z = f2bf(tile[tc + 2][dr]);
      o.w = f2bf(tile[tc + 3][dr]);
      *(ushort4*)(vT + (size_t)(d0 + dr) * 2048 + s0 + tc) = o;
    }
    return;
  }
  // ---- RMSNorm + RoPE path ----
  const int s = blockIdx.x;
  const u16* src = qkv + (size_t)s * 6144 + which * 2048;
  const float* bias = which ? bk : bq;
  const float* g = which ? gk : gq;
  u16* dst = (which ? kb : qb) + (size_t)s * 2048;
  const int c0 = t * 8;
  uint4 raw = *(const uint4*)(src + c0);         // 8 bf16
  const u16* rp = (const u16*)&raw;
  float4 b0 = *(const float4*)(bias + c0);
  float4 b1 = *(const float4*)(bias + c0 + 4);
  float v[8];
  v[0] = b2f(rp[0]) + b0.x; v[1] = b2f(rp[1]) + b0.y;
  v[2] = b2f(rp[2]) + b0.z; v[3] = b2f(rp[3]) + b0.w;
  v[4] = b2f(rp[4]) + b1.x; v[5] = b2f(rp[5]) + b1.y;
  v[6] = b2f(rp[6]) + b1.z; v[7] = b2f(rp[7]) + b1.w;
  float ss = 0.f;
#pragma unroll
  for (int j = 0; j < 8; ++j) ss += v[j] * v[j];
#pragma unroll
  for (int m = 1; m < 64; m <<= 1) ss += __shfl_xor(ss, m);
  __shared__ float red[4];
  if ((t & 63) == 0) red[t >> 6] = ss;
  __syncthreads();
  float r = rsqrtf((red[0] + red[1] + red[2] + red[3]) * (1.0f / 2048.0f) + 1e-6f);
  if (!which) r *= 0.08838834764831843f * 1.4426950408889634f;
  float4 g0 = *(const float4*)(g + c0);
  float4 g1 = *(const float4*)(g + c0 + 4);
  float gg[8] = {g0.x, g0.y, g0.z, g0.w, g1.x, g1.y, g1.z, g1.w};
  const int p0 = (c0 & 127) >> 1;
  u16 o[8];
#pragma unroll
  for (int j = 0; j < 4; ++j) {
    float a = v[2 * j] * r * gg[2 * j];
    float b = v[2 * j + 1] * r * gg[2 * j + 1];
    float co = fcos[s * 64 + p0 + j], si = fsin[s * 64 + p0 + j];
    o[2 * j]     = f2bf(a * co - b * si);
    o[2 * j + 1] = f2bf(a * si + b * co);
  }
  ushort4 q0; q0.x = o[0]; q0.y = o[1]; q0.z = o[2]; q0.w = o[3];
  ushort4 q1; q1.x = o[4]; q1.y = o[5]; q1.z = o[6]; q1.w = o[7];
  *(ushort4*)(dst + c0) = q0;
  *(ushort4*)(dst + c0 + 4) = q1;
}

// ---------------- flash attention: swapped QK^T, in-register softmax ----------
// flat grid 512, decode: xcd (bid&7) owns heads {2x,2x+1} -> K/V/Q L2-resident.
// 4 waves x 32 q-rows, 32x32x16 MFMA. K,V double-buffered, r10 schedule.
// lsum computed on the MATRIX pipe: o4 += mfma(pa[s], ones) accumulates the
// row-sum of P (V==1). Defer-rescale multiplies o4 along with o. Epilogue
// extracts lsum[q] from o4 via unrolled cndmask select (static idx) + one shfl.
__global__ __launch_bounds__(256, 2) void k_attn(const u16* __restrict__ qb,
                                                 const u16* __restrict__ kb,
                                                 const u16* __restrict__ vT,
                                                 float* __restrict__ opart,
                                                 float* __restrict__ ml) {
  __shared__ __align__(16) char Ks[2][16384];    // K tile [64 keys][128 d]
  __shared__ __align__(16) char Vs[2][16384];    // V tile [128 d][64 k]
  const int bid = blockIdx.x;
  const int xcd = bid & 7, j = bid >> 3;         // j in 0..63
  const int h = xcd * 2 + (j & 1);
  const int qt = (j >> 1) & 15;
  const int ks = j >> 5;
  const int tid = threadIdx.x;
  const int wid = tid >> 6, lane = tid & 63;
  const int l31 = lane & 31, hi = lane >> 5;
  const int q0w = qt * 128 + wid * 32;
  const char* kbB = (const char*)kb;
  const char* vTB = (const char*)vT;
  const int krow = tid >> 4;                     // K: 16 rows/issue, 256B rows
  const int kc = (tid & 15) ^ krow;              // 4-bit XOR (16 chunks/row)
  const int vrow = tid >> 3;                     // V: 32 rows/issue, 128B rows
  const int vc = (tid & 7) ^ (vrow & 7);         // 3-bit XOR (8 chunks/row)

#define STAGE(buf, k0)                                                         \
  {                                                                            \
    _Pragma("unroll") for (int i = 0; i < 4; ++i)                              \
        gload_lds16(kbB + (size_t)((k0) + i * 16 + krow) * 4096 + h * 256 +    \
                        kc * 16,                                               \
                    (char*)Ks + (buf) * 16384 + i * 4096 + wid * 1024);        \
    _Pragma("unroll") for (int i = 0; i < 4; ++i)                              \
        gload_lds16(vTB + (size_t)(h * 128 + i * 32 + vrow) * 4096 +           \
                        (size_t)(k0) * 2 + vc * 16,                            \
                    (char*)Vs + (buf) * 16384 + i * 4096 + wid * 1024);        \
  }

  // Q fragments: B-operand, col q = l31, d-elems = ds*16 + hi*8 .. +8
  bf16x8 qf[8];
#pragma unroll
  for (int ds = 0; ds < 8; ++ds)
    qf[ds] = *(const bf16x8*)(qb + (size_t)(q0w + l31) * 2048 + h * 128 +
                              ds * 16 + hi * 8);
  f32x16 o[4] = {};                              // O[q reg-mapped][dt*32+l31]
  f32x16 o4 = {};                                // row-sum accumulator (V==1)
  float mrun = -3.0e38f;
  const int kbeg = ks * 1024;
  const int ksw = l31 & 15, vsw = l31 & 7;       // read-side swizzle keys
  union { u32 w[4]; bf16x8 v; } onesu;
  onesu.w[0] = 0x3F803F80u; onesu.w[1] = 0x3F803F80u;
  onesu.w[2] = 0x3F803F80u; onesu.w[3] = 0x3F803F80u;
  const bf16x8 vones = onesu.v;
  STAGE(0, kbeg);
  __syncthreads();
  int cur = 0;
  for (int t = 0; t < 16; ++t) {
    if (t + 1 < 16) STAGE(cur ^ 1, kbeg + (t + 1) * 64);
    const char* Kc = Ks[cur];
    const char* Vc = Vs[cur];
    // QK^T swapped: p[h2] = K[h2*32..+32) x Q  -> D[k][q]
    f32x16 p0 = {}, p1 = {};
    __builtin_amdgcn_s_setprio(1);
#pragma unroll
    for (int ds = 0; ds < 8; ++ds) {
      bf16x8 kf0 = *(const bf16x8*)(Kc + l31 * 256 + (((ds * 2 + hi) ^ ksw) * 16));
      p0 = __builtin_amdgcn_mfma_f32_32x32x16_bf16(kf0, qf[ds], p0, 0, 0, 0);
      bf16x8 kf1 = *(const bf16x8*)(Kc + (32 + l31) * 256 +
                                    (((ds * 2 + hi) ^ ksw) * 16));
      p1 = __builtin_amdgcn_mfma_f32_32x32x16_bf16(kf1, qf[ds], p1, 0, 0, 0);
    }
    __builtin_amdgcn_s_setprio(0);
    // row max: pairwise tree, depth 5
    {
      float tm[8];
#pragma unroll
      for (int r = 0; r < 8; ++r)
        tm[r] = fmaxf(fmaxf(p0[2 * r], p0[2 * r + 1]),
                      fmaxf(p1[2 * r], p1[2 * r + 1]));
#pragma unroll
      for (int s = 4; s > 0; s >>= 1)
#pragma unroll
        for (int r = 0; r < s; ++r) tm[r] = fmaxf(tm[r], tm[r + s]);
      float pm = fmaxf(tm[0], __shfl_xor(tm[0], 32));
      // T13 defer-rescale (log2 domain, THR=8 -> P bounded by 2^8)
      if (!__all(pm <= mrun + 8.0f)) {
        float nm = fmaxf(mrun, pm);
        float fv = __builtin_amdgcn_exp2f(mrun - nm);
#pragma unroll
        for (int dt = 0; dt < 4; ++dt) o[dt] *= fv;
        o4 *= fv;
        mrun = nm;
      }
    }
#pragma unroll
    for (int r = 0; r < 16; ++r) p0[r] = __builtin_amdgcn_exp2f(p0[r] - mrun);
#pragma unroll
    for (int r = 0; r < 16; ++r) p1[r] = __builtin_amdgcn_exp2f(p1[r] - mrun);
    // P -> PA fragments via cvt_pk + permlane32_swap (no LDS roundtrip)
    bf16x8 pa[4];
#pragma unroll
    for (int sl = 0; sl < 2; ++sl) {
      u32 E0 = cvtpk(p0[8 * sl + 0], p0[8 * sl + 1]);
      u32 E1 = cvtpk(p0[8 * sl + 2], p0[8 * sl + 3]);
      u32 O0 = cvtpk(p0[8 * sl + 4], p0[8 * sl + 5]);
      u32 O1 = cvtpk(p0[8 * sl + 6], p0[8 * sl + 7]);
      pswap(E0, O0); pswap(E1, O1);
      union { u32 w[4]; bf16x8 v; } uu;
      uu.w[0] = E0; uu.w[1] = E1; uu.w[2] = O0; uu.w[3] = O1;
      pa[sl] = uu.v;
    }
#pragma unroll
    for (int sl = 0; sl < 2; ++sl) {
      u32 E0 = cvtpk(p1[8 * sl + 0], p1[8 * sl + 1]);
      u32 E1 = cvtpk(p1[8 * sl + 2], p1[8 * sl + 3]);
      u32 O0 = cvtpk(p1[8 * sl + 4], p1[8 * sl + 5]);
      u32 O1 = cvtpk(p1[8 * sl + 6], p1[8 * sl + 7]);
      pswap(E0, O0); pswap(E1, O1);
      union { u32 w[4]; bf16x8 v; } uu;
      uu.w[0] = E0; uu.w[1] = E1; uu.w[2] = O0; uu.w[3] = O1;
      pa[2 + sl] = uu.v;
    }
    // PV: O[q][d] += PA[q][16k] x V[16k][32d]; o4 += PA x ones (row-sum)
    __builtin_amdgcn_s_setprio(1);
#pragma unroll
    for (int s = 0; s < 4; ++s) {
#pragma unroll
      for (int dt = 0; dt < 4; ++dt) {
        bf16x8 vf = *(const bf16x8*)(Vc + (dt * 32 + l31) * 128 +
                                     (((s * 2 + hi) ^ vsw) * 16));
        o[dt] = __builtin_amdgcn_mfma_f32_32x32x16_bf16(pa[s], vf, o[dt], 0, 0, 0);
      }
      o4 = __builtin_amdgcn_mfma_f32_32x32x16_bf16(pa[s], vones, o4, 0, 0, 0);
    }
    __builtin_amdgcn_s_setprio(0);
    __syncthreads();                             // stage done + bufs consumed
    cur ^= 1;
  }
#undef STAGE
  // write unnormalized partials; q_row(r) = (r&3) + 8*(r>>2) + 4*hi
  float* opb = opart + ((size_t)ks * 32768 + (size_t)h * 2048 + q0w) * 128 + l31;
#pragma unroll
  for (int dt = 0; dt < 4; ++dt)
#pragma unroll
    for (int r = 0; r < 16; ++r)
      opb[(size_t)((r & 3) + 8 * (r >> 2) + 4 * hi) * 128 + dt * 32] = o[dt][r];
  // lsum for q = l31 lives in o4[rsel] of the lane-half with hi == (q>>2)&1
  {
    const int rsel = (l31 & 3) | (((l31 >> 3) & 3) << 2);
    float cand = o4[0];
#pragma unroll
    for (int r = 1; r < 16; ++r) cand = (rsel == r) ? o4[r] : cand;
    float other = __shfl_xor(cand, 32);
    float lsum_q = (hi == ((l31 >> 2) & 1)) ? cand : other;
    if (lane < 32) {
      float2 v2; v2.x = mrun; v2.y = lsum_q;
      *(float2*)(ml + ((size_t)ks * 32768 + (size_t)h * 2048 + q0w + l31) * 2) = v2;
    }
  }
}

// ---------------- merge 2 k-split partials -> ao bf16 [s][h*128+d] -----------
__global__ __launch_bounds__(256) void k_attn_merge(const float* __restrict__ opart,
                                                    const float* __restrict__ ml,
                                                    u16* __restrict__ ob) {
  const int r = blockIdx.x * 8 + (threadIdx.x >> 5);   // r = h*2048 + q
  const int d0 = (threadIdx.x & 31) * 4;
  float2 ml0 = *(const float2*)(ml + (size_t)r * 2);
  float2 ml1 = *(const float2*)(ml + (size_t)(32768 + r) * 2);
  float M = fmaxf(ml0.x, ml1.x);
  float f0 = __builtin_amdgcn_exp2f(ml0.x - M);
  float f1 = __builtin_amdgcn_exp2f(ml1.x - M);
  float inv = 1.0f / (ml0.y * f0 + ml1.y * f1);
  float4 a = *(const float4*)(opart + (size_t)r * 128 + d0);
  float4 b = *(const float4*)(opart + (size_t)(32768 + r) * 128 + d0);
  int h = r >> 11, q = r & 2047;
  ushort4 o;
  o.x = f2bf((a.x * f0 + b.x * f1) * inv);
  o.y = f2bf((a.y * f0 + b.y * f1) * inv);
  o.z = f2bf((a.z * f0 + b.z * f1) * inv);
  o.w = f2bf((a.w * f0 + b.w * f1) * inv);
  *(ushort4*)(ob + (size_t)q * 2048 + h * 128 + d0) = o;
}

// -----------------------------------------------------------------------------
extern "C" void kernel_launch(void* const* d_in, const int* in_sizes, int n_in,
                              void* d_out, int out_size, void* d_ws, size_t ws_size,
                              hipStream_t stream) {
  const float* x    = (const float*)d_in[0];
  const float* wq   = (const float*)d_in[1];
  const float* bq   = (const float*)d_in[2];
  const float* wk   = (const float*)d_in[3];
  const float* bk   = (const float*)d_in[4];
  const float* wv   = (const float*)d_in[5];
  const float* bv   = (const float*)d_in[6];
  const float* wo   = (const float*)d_in[7];
  const float* bo   = (const float*)d_in[8];
  const float* gq   = (const float*)d_in[9];
  const float* gk   = (const float*)d_in[10];
  const float* fcos = (const float*)d_in[11];
  const float* fsin = (const float*)d_in[12];

  // ws layout (92,274,688 B total; lifetime-overlapped):
  //   [0, 25165824)            qkv_pre bf16 (phase A) | opart+ml (attn phase)
  //   [50331648, 58720256)     xb bf16 (phase A)   | qb bf16 (phase B+)
  //   [58720256, 83886080)     wqkv bf16 (phase A) | kb, vT, ao bf16 (phase B+)
  //   [83886080, 92274688)     wob bf16 (whole call)
  char* ws = (char*)d_ws;
  u16* qkv_pre = (u16*)ws;                      // 2048 x 6144 bf16 = 25.2 MB
  float* opart = (float*)ws;                    // 2 x 32768 x 128 fp32 = 32 MB
  float* ml    = (float*)(ws + 33554432);       // 2 x 32768 x 2 fp32 = 512 KB
  u16* xb   = (u16*)(ws + 50331648);
  u16* wqkv = (u16*)(ws + 58720256);
  u16* qb   = (u16*)(ws + 50331648);
  u16* kb   = (u16*)(ws + 58720256);
  u16* vT   = (u16*)(ws + 67108864);
  u16* ao   = (u16*)(ws + 75497472);
  u16* wob  = (u16*)(ws + 83886080);

  k_cvt5<<<dim3(4096, 5), 256, 0, stream>>>(x, wq, wk, wv, wo, xb, wqkv, wob);

  // q|k|v = x @ [wq;wk;wv]^T  (bias applied downstream)
  k_gemm_big<<<512, 512, 0, stream>>>(xb, wqkv, qkv_pre, 2048, 6144, 2048);
  k_prep<<<dim3(2048, 3), 256, 0, stream>>>(qkv_pre, bq, bk, bv, gq, gk,
                                            fcos, fsin, qb, kb, vT);
  k_attn<<<512, 256, 0, stream>>>(qb, kb, vT, opart, ml);
  k_attn_merge<<<4096, 256, 0, stream>>>(opart, ml, ao);
  k_gemm_pipe<<<dim3(512), 256, 0, stream>>>(ao, wob, bo, (float*)d_out,
                                             2048, 2048, 2048);
}